// Round 3
// baseline (664.063 us; speedup 1.0000x reference)
//
#include <hip/hip_runtime.h>

typedef unsigned short ushort_t;
typedef unsigned int   uint_t;
typedef __attribute__((ext_vector_type(8))) short  short8;
typedef __attribute__((ext_vector_type(4))) float  floatx4;

#define NROWS 131072
#define BM    32
#define SX    328     // x-hat bf16 LDS stride (ushorts)
#define SXR   300     // raw x fp32 LDS stride (floats)
#define SH    264     // h bf16 LDS stride (ushorts)

// d_ws bf16 region (ushort element offsets)
#define W1_OFF 0
#define P1_OFF 74752
#define W2_OFF 149504
#define P2_OFF 215040
#define BF16_BYTES 561152
// d_ws float region (float element offsets, base = ws + BF16_BYTES)
#define B1_OFF  0
#define PB1_OFF 256
#define B2_OFF  512
#define PB2_OFF 768
#define W3_OFF  1024
#define P3_OFF  1280
#define B3_OFF  3840
#define PB3_OFF 3841

__device__ __forceinline__ float b2f(ushort_t u){
    union { uint_t i; float f; } v; v.i = ((uint_t)u) << 16; return v.f;
}
__device__ __forceinline__ ushort_t f2b(float f){
    union { uint_t i; float f; } v; v.f = f;
    uint_t b = v.i;
    b += 0x7FFFu + ((b >> 16) & 1u);   // RNE
    return (ushort_t)(b >> 16);
}

// ---------------- prologue: fold LN gain/bias into linears, fp32 -> bf16 ----
__global__ __launch_bounds__(256) void bcq_prep(
    const float* __restrict__ ln1w, const float* __restrict__ ln1b,
    const float* __restrict__ ln2w, const float* __restrict__ ln2b,
    const float* __restrict__ ln3w, const float* __restrict__ ln3b,
    const float* __restrict__ n1g,  const float* __restrict__ n1b,
    const float* __restrict__ n2g,  const float* __restrict__ n2b,
    const float* __restrict__ n3g,  const float* __restrict__ n3b,
    const float* __restrict__ p1w,  const float* __restrict__ p1b,
    const float* __restrict__ p2w,  const float* __restrict__ p2b,
    const float* __restrict__ p3w,  const float* __restrict__ p3b,
    const float* __restrict__ pn1g, const float* __restrict__ pn1b,
    const float* __restrict__ pn2g, const float* __restrict__ pn2b,
    const float* __restrict__ pn3g, const float* __restrict__ pn3b,
    ushort_t* __restrict__ wbf, float* __restrict__ wf)
{
    const int bid = blockIdx.x, tid = threadIdx.x;
    if (bid < 128){
        for (int i = bid*256 + tid; i < 280576; i += 128*256){
            if (i < 74752){        int k = i % 292;                 wbf[W1_OFF + i] = f2b(ln1w[i]*n1g[k]); }
            else if (i < 149504){  int j = i - 74752;  int k = j % 292; wbf[P1_OFF + j] = f2b(p1w[j]*pn1g[k]); }
            else if (i < 215040){  int j = i - 149504; int k = j & 255; wbf[W2_OFF + j] = f2b(ln2w[j]*n2g[k]); }
            else {                 int j = i - 215040; int k = j & 255; wbf[P2_OFF + j] = f2b(p2w[j]*pn2g[k]); }
        }
    } else if (bid == 128){
        float s = ln1b[tid];
        for (int k = 0; k < 292; ++k) s += ln1w[tid*292 + k]*n1b[k];
        wf[B1_OFF + tid] = s;
    } else if (bid == 129){
        float s = p1b[tid];
        for (int k = 0; k < 292; ++k) s += p1w[tid*292 + k]*pn1b[k];
        wf[PB1_OFF + tid] = s;
    } else if (bid == 130){
        float s = ln2b[tid];
        for (int k = 0; k < 256; ++k) s += ln2w[tid*256 + k]*n2b[k];
        wf[B2_OFF + tid] = s;
    } else if (bid == 131){
        float s = p2b[tid];
        for (int k = 0; k < 256; ++k) s += p2w[tid*256 + k]*pn2b[k];
        wf[PB2_OFF + tid] = s;
    } else {
        wf[W3_OFF + tid] = ln3w[tid]*n3g[tid];
        for (int i = tid; i < 2560; i += 256){ int k = i & 255; wf[P3_OFF + i] = p3w[i]*pn3g[k]; }
        if (tid == 0){
            float s = ln3b[0];
            for (int k = 0; k < 256; ++k) s += ln3w[k]*n3b[k];
            wf[B3_OFF] = s;
        }
        if (tid >= 64 && tid < 74){
            int j = tid - 64;
            float s = p3b[j];
            for (int k = 0; k < 256; ++k) s += p3w[j*256 + k]*pn3b[k];
            wf[PB3_OFF + j] = s;
        }
    }
}

// ---------------- main ------------------------------------------------------
// GEMM: sOut[32x256] = relu( sIn[32xK] @ W'^T + b' ). Waves: 32 rows x 64 cols
// each (one B fragment feeds 2 MFMAs). W' bf16 row-major [256 x K] in ws.
__device__ __forceinline__ void gemm32(
    const ushort_t* sIn, int stride, const ushort_t* __restrict__ Wg, int K,
    int fullKC, bool tail, const float* __restrict__ biasf, ushort_t* sOut, int tid)
{
    const int lane = tid & 63, wave = tid >> 6;
    const int l15 = lane & 15, quad = lane >> 4;
    const int colbase = wave * 64;
    const ushort_t* ar0 = sIn + l15*stride;
    const ushort_t* ar1 = sIn + (16 + l15)*stride;
    const ushort_t* wp[4];
#pragma unroll
    for (int nt = 0; nt < 4; ++nt)
        wp[nt] = Wg + (size_t)(colbase + nt*16 + l15) * K;

    floatx4 acc[4][2];
#pragma unroll
    for (int nt = 0; nt < 4; ++nt){ acc[nt][0] = (floatx4){0,0,0,0}; acc[nt][1] = (floatx4){0,0,0,0}; }

    for (int kc = 0; kc < fullKC; ++kc){
        const int kb = kc * 32;
        short8 a0 = *(const short8*)(ar0 + kb + quad*8);
        short8 a1 = *(const short8*)(ar1 + kb + quad*8);
#pragma unroll
        for (int nt = 0; nt < 4; ++nt){
            union { uint_t u[4]; short8 s; } bu;
            const uint_t* wq = (const uint_t*)(wp[nt] + kb + quad*8);
            bu.u[0] = wq[0]; bu.u[1] = wq[1]; bu.u[2] = wq[2]; bu.u[3] = wq[3];
            acc[nt][0] = __builtin_amdgcn_mfma_f32_16x16x32_bf16(a0, bu.s, acc[nt][0], 0, 0, 0);
            acc[nt][1] = __builtin_amdgcn_mfma_f32_16x16x32_bf16(a1, bu.s, acc[nt][1], 0, 0, 0);
        }
    }
    if (tail){   // K=292: k 288..291 valid; sIn zero-padded to 320
        const int kb = fullKC * 32;
        short8 a0 = *(const short8*)(ar0 + kb + quad*8);
        short8 a1 = *(const short8*)(ar1 + kb + quad*8);
#pragma unroll
        for (int nt = 0; nt < 4; ++nt){
            union { uint_t u[4]; short8 s; } bu;
            bu.u[0] = 0; bu.u[1] = 0; bu.u[2] = 0; bu.u[3] = 0;
            if (quad == 0){
                const uint_t* wq = (const uint_t*)(wp[nt] + kb);
                bu.u[0] = wq[0]; bu.u[1] = wq[1];
            }
            acc[nt][0] = __builtin_amdgcn_mfma_f32_16x16x32_bf16(a0, bu.s, acc[nt][0], 0, 0, 0);
            acc[nt][1] = __builtin_amdgcn_mfma_f32_16x16x32_bf16(a1, bu.s, acc[nt][1], 0, 0, 0);
        }
    }
    // epilogue: C/D layout col=lane&15, row=quad*4+i
#pragma unroll
    for (int nt = 0; nt < 4; ++nt){
        const int col = colbase + nt*16 + l15;
        const float bia = biasf[col];
#pragma unroll
        for (int s2 = 0; s2 < 2; ++s2){
#pragma unroll
            for (int i = 0; i < 4; ++i){
                const int row = s2*16 + quad*4 + i;
                float v = acc[nt][s2][i] + bia;
                v = fmaxf(v, 0.f);
                sOut[row*SH + col] = f2b(v);
            }
        }
    }
}

// plain LN (gain/bias already folded downstream): sOut = (sIn - m)*rstd
__device__ __forceinline__ void ln256(
    const ushort_t* sIn, ushort_t* sOut, float* sRed, float* sM, float* sR, int tid)
{
    const int r = tid >> 3, p = tid & 7;
    const ushort_t* hp = sIn + r*SH + p*32;
    float s = 0.f, sq = 0.f;
#pragma unroll
    for (int c = 0; c < 32; ++c){ float x = b2f(hp[c]); s += x; sq += x*x; }
    sRed[tid] = s; sRed[256 + tid] = sq;
    __syncthreads();
    if (tid < 32){
        float ss = 0.f, qq = 0.f;
#pragma unroll
        for (int j = 0; j < 8; ++j){ ss += sRed[tid*8 + j]; qq += sRed[256 + tid*8 + j]; }
        float m = ss * (1.f/256.f);
        float var = fmaxf(qq * (1.f/256.f) - m*m, 0.f);
        sM[tid] = m; sR[tid] = rsqrtf(var + 1e-5f);
    }
    __syncthreads();
#pragma unroll 4
    for (int r2 = 0; r2 < 32; ++r2)
        sOut[r2*SH + tid] = f2b((b2f(sIn[r2*SH + tid]) - sM[r2]) * sR[r2]);
    __syncthreads();
}

__global__ __launch_bounds__(256, 2) void bcq_main(
    const float* __restrict__ cum, const float* __restrict__ inp, const float* __restrict__ pos,
    const ushort_t* __restrict__ wbf, const float* __restrict__ wf, float* __restrict__ out)
{
    __shared__ __align__(16) char sMem[62976];
    float*    sXr    = (float*)sMem;                 // phase 0 only (38400 B)
    ushort_t* sH     = (ushort_t*)sMem;              // towers (16896 B)
    ushort_t* sHn    = (ushort_t*)(sMem + 16896);    // towers (16896 B)
    ushort_t* sX     = (ushort_t*)(sMem + 38400);    // x-hat  (20992 B)
    float*    sRed   = (float*)(sMem + 59392);       // 2048 B
    float*    sM     = (float*)(sMem + 61440);       // 128 B
    float*    sR     = (float*)(sMem + 61568);       // 128 B
    float*    sScore = (float*)(sMem + 61696);       // 1280 B

    const int tid = threadIdx.x;
    const size_t rowg = (size_t)blockIdx.x * BM;

    // ---- stage raw x (coalesced fp32) ----
    for (int i = tid; i < 32*146; i += 256){ int r = i/146, c = i - r*146; sXr[r*SXR + c]       = cum[(rowg+r)*146 + c]; }
    for (int i = tid; i < 32*136; i += 256){ int r = i/136, c = i - r*136; sXr[r*SXR + 146 + c] = inp[(rowg+r)*136 + c]; }
    for (int i = tid; i < 32*10;  i += 256){ int r = i/10,  c = i - r*10;  sXr[r*SXR + 282 + c] = pos[(rowg+r)*10  + c]; }
    __syncthreads();

    // ---- LN1 stats over 292 ----
    {
        const int r = tid >> 3, p = tid & 7;
        float s = 0.f, sq = 0.f;
#pragma unroll
        for (int i = 0; i < 37; ++i){
            const int c = p + (i << 3);
            if (c < 292){ float x = sXr[r*SXR + c]; s += x; sq += x*x; }
        }
        sRed[tid] = s; sRed[256 + tid] = sq;
    }
    __syncthreads();
    if (tid < 32){
        float ss = 0.f, qq = 0.f;
#pragma unroll
        for (int j = 0; j < 8; ++j){ ss += sRed[tid*8 + j]; qq += sRed[256 + tid*8 + j]; }
        float m = ss * (1.f/292.f);
        float var = fmaxf(qq * (1.f/292.f) - m*m, 0.f);
        sM[tid] = m; sR[tid] = rsqrtf(var + 1e-5f);
    }
    __syncthreads();

    // ---- build x-hat (bf16), zero-pad K=[292,320) ----
    {
#pragma unroll 4
        for (int r = 0; r < 32; ++r)
            sX[r*SX + tid] = f2b((sXr[r*SXR + tid] - sM[r]) * sR[r]);
        if (tid < 36){
            const int c = 256 + tid;
#pragma unroll 4
            for (int r = 0; r < 32; ++r)
                sX[r*SX + c] = f2b((sXr[r*SXR + c] - sM[r]) * sR[r]);
        }
        if (tid >= 228){
            const int c = 292 + (tid - 228);   // 292..319
#pragma unroll 4
            for (int r = 0; r < 32; ++r) sX[r*SX + c] = 0;
        }
    }
    __syncthreads();   // sXr dead from here; sH/sHn alias it

    // ================= value tower =================
    gemm32(sX, SX, wbf + W1_OFF, 292, 9, true,  wf + B1_OFF, sH, tid);
    __syncthreads();
    ln256(sH, sHn, sRed, sM, sR, tid);
    gemm32(sHn, SH, wbf + W2_OFF, 256, 8, false, wf + B2_OFF, sH, tid);
    __syncthreads();
    ln256(sH, sHn, sRed, sM, sR, tid);
    {   // value head
        const int r = tid >> 3, p = tid & 7;
        const ushort_t* ap = sHn + r*SH + p*32;
        const float* w3 = wf + W3_OFF + p*32;
        float s = 0.f;
#pragma unroll
        for (int c = 0; c < 32; ++c) s += b2f(ap[c]) * w3[c];
        sRed[tid] = s;
        __syncthreads();
        if (tid < 32){
            float v = wf[B3_OFF];
#pragma unroll
            for (int j = 0; j < 8; ++j) v += sRed[tid*8 + j];
            out[rowg + tid] = v;
        }
        __syncthreads();
    }

    // ================= probability tower =================
    gemm32(sX, SX, wbf + P1_OFF, 292, 9, true,  wf + PB1_OFF, sH, tid);
    __syncthreads();
    ln256(sH, sHn, sRed, sM, sR, tid);
    gemm32(sHn, SH, wbf + P2_OFF, 256, 8, false, wf + PB2_OFF, sH, tid);
    __syncthreads();
    ln256(sH, sHn, sRed, sM, sR, tid);
    {   // score head + log_softmax
        for (int s2 = tid; s2 < 320; s2 += 256){
            const int r = s2 / 10, j = s2 - r*10;
            const ushort_t* ap = sHn + r*SH;
            const float* pw = wf + P3_OFF + j*256;
            float acc = 0.f;
            for (int c = 0; c < 256; ++c) acc += b2f(ap[c]) * pw[c];
            sScore[s2] = acc + wf[PB3_OFF + j];
        }
        __syncthreads();
        if (tid < 32){
            float m = -1e30f;
#pragma unroll
            for (int j = 0; j < 10; ++j) m = fmaxf(m, sScore[tid*10 + j]);
            float l = 0.f;
#pragma unroll
            for (int j = 0; j < 10; ++j) l += expf(sScore[tid*10 + j] - m);
            l = logf(l);
            const size_t rg = rowg + tid;
#pragma unroll
            for (int j = 0; j < 10; ++j){
                const float sv = sScore[tid*10 + j];
                out[(size_t)NROWS    + rg*10 + j] = sv - m - l;
                out[(size_t)NROWS*11 + rg*10 + j] = sv;
            }
        }
    }
}

extern "C" void kernel_launch(void* const* d_in, const int* in_sizes, int n_in,
                              void* d_out, int out_size, void* d_ws, size_t ws_size,
                              hipStream_t stream) {
    (void)in_sizes; (void)n_in; (void)ws_size; (void)out_size;
    const float* cum  = (const float*)d_in[0];
    const float* inp  = (const float*)d_in[1];
    const float* pos  = (const float*)d_in[2];
    const float* ln1w = (const float*)d_in[3];
    const float* ln1b = (const float*)d_in[4];
    const float* ln2w = (const float*)d_in[5];
    const float* ln2b = (const float*)d_in[6];
    const float* ln3w = (const float*)d_in[7];
    const float* ln3b = (const float*)d_in[8];
    const float* n1g  = (const float*)d_in[9];
    const float* n1b  = (const float*)d_in[10];
    const float* n2g  = (const float*)d_in[11];
    const float* n2b  = (const float*)d_in[12];
    const float* n3g  = (const float*)d_in[13];
    const float* n3b  = (const float*)d_in[14];
    const float* p1w  = (const float*)d_in[15];
    const float* p1b  = (const float*)d_in[16];
    const float* p2w  = (const float*)d_in[17];
    const float* p2b  = (const float*)d_in[18];
    const float* p3w  = (const float*)d_in[19];
    const float* p3b  = (const float*)d_in[20];
    const float* pn1g = (const float*)d_in[21];
    const float* pn1b = (const float*)d_in[22];
    const float* pn2g = (const float*)d_in[23];
    const float* pn2b = (const float*)d_in[24];
    const float* pn3g = (const float*)d_in[25];
    const float* pn3b = (const float*)d_in[26];

    ushort_t* wbf = (ushort_t*)d_ws;
    float*    wf  = (float*)((char*)d_ws + BF16_BYTES);
    float*    out = (float*)d_out;

    hipLaunchKernelGGL(bcq_prep, dim3(133), dim3(256), 0, stream,
        ln1w, ln1b, ln2w, ln2b, ln3w, ln3b,
        n1g, n1b, n2g, n2b, n3g, n3b,
        p1w, p1b, p2w, p2b, p3w, p3b,
        pn1g, pn1b, pn2g, pn2b, pn3g, pn3b,
        wbf, wf);

    hipLaunchKernelGGL(bcq_main, dim3(NROWS/BM), dim3(256), 0, stream,
        cum, inp, pos, wbf, wf, out);
}

// Round 4
// 617.251 us; speedup vs baseline: 1.0758x; 1.0758x over previous
//
#include <hip/hip_runtime.h>

typedef unsigned short ushort_t;
typedef unsigned int   uint_t;
typedef __attribute__((ext_vector_type(8))) short  short8;
typedef __attribute__((ext_vector_type(4))) float  floatx4;

#define NROWS 131072
#define BM    32
#define SX    328     // x-hat bf16 LDS row stride (ushorts); cols >=292 zeroed to 320
#define SH    264     // h bf16 LDS row stride (ushorts)
#define KS1   320     // padded K-stride of layer-1 weights (16B-aligned rows, zero tail)

// d_ws bf16 region (ushort element offsets)
#define W1_OFF 0
#define P1_OFF 81920
#define W2_OFF 163840
#define P2_OFF 229376
#define BF16_BYTES 589824
// d_ws float region (float element offsets, base = ws + BF16_BYTES)
#define B1_OFF  0
#define PB1_OFF 256
#define B2_OFF  512
#define PB2_OFF 768
#define W3_OFF  1024
#define P3_OFF  1280
#define B3_OFF  3840
#define PB3_OFF 3841

__device__ __forceinline__ float b2f(ushort_t u){
    union { uint_t i; float f; } v; v.i = ((uint_t)u) << 16; return v.f;
}
__device__ __forceinline__ ushort_t f2b(float f){
    union { uint_t i; float f; } v; v.f = f;
    uint_t b = v.i;
    b += 0x7FFFu + ((b >> 16) & 1u);   // RNE
    return (ushort_t)(b >> 16);
}

// ---------------- prologue: fold LN gain/bias into linears, fp32 -> bf16 ----
// blocks 0..127   : weight convert (layer1 padded to KS1, layer2 direct)
// blocks 128..383 : 1024 bias-fold dots, one wave each
// block  384      : W3, P3 scalar folds
// blocks 385..386 : B3 + PB3 dots (32-lane groups)
__global__ __launch_bounds__(256) void bcq_prep(
    const float* __restrict__ ln1w, const float* __restrict__ ln1b,
    const float* __restrict__ ln2w, const float* __restrict__ ln2b,
    const float* __restrict__ ln3w, const float* __restrict__ ln3b,
    const float* __restrict__ n1g,  const float* __restrict__ n1b,
    const float* __restrict__ n2g,  const float* __restrict__ n2b,
    const float* __restrict__ n3g,  const float* __restrict__ n3b,
    const float* __restrict__ p1w,  const float* __restrict__ p1b,
    const float* __restrict__ p2w,  const float* __restrict__ p2b,
    const float* __restrict__ p3w,  const float* __restrict__ p3b,
    const float* __restrict__ pn1g, const float* __restrict__ pn1b,
    const float* __restrict__ pn2g, const float* __restrict__ pn2b,
    const float* __restrict__ pn3g, const float* __restrict__ pn3b,
    ushort_t* __restrict__ wbf, float* __restrict__ wf)
{
    const int bid = blockIdx.x, tid = threadIdx.x;
    if (bid < 128){
        for (int i = bid*256 + tid; i < 163840; i += 128*256){
            const int col = i / KS1, k = i - col*KS1;       // col 0..511
            const float* src = (col < 256) ? ln1w : p1w;
            const float* g   = (col < 256) ? n1g  : pn1g;
            const int c = col & 255;
            ushort_t v = 0;
            if (k < 292) v = f2b(src[c*292 + k] * g[k]);
            wbf[i] = v;                                      // W1 then P1, contiguous
        }
        for (int i = bid*256 + tid; i < 131072; i += 128*256){
            const int col = i >> 8, k = i & 255;
            const float* src = (col < 256) ? ln2w : p2w;
            const float* g   = (col < 256) ? n2g  : pn2g;
            const int c = col & 255;
            wbf[W2_OFF + i] = f2b(src[c*256 + k] * g[k]);
        }
    } else if (bid < 384){
        const int d = (bid - 128)*4 + (tid >> 6);
        const int lane = tid & 63;
        const float *w, *nb, *bs; int K, outoff; const int c = d & 255;
        if (d < 256)      { w = ln1w; nb = n1b;  bs = ln1b; K = 292; outoff = B1_OFF; }
        else if (d < 512) { w = p1w;  nb = pn1b; bs = p1b;  K = 292; outoff = PB1_OFF; }
        else if (d < 768) { w = ln2w; nb = n2b;  bs = ln2b; K = 256; outoff = B2_OFF; }
        else              { w = p2w;  nb = pn2b; bs = p2b;  K = 256; outoff = PB2_OFF; }
        float s = 0.f;
        for (int k = lane; k < K; k += 64) s += w[c*K + k] * nb[k];
        for (int off = 32; off; off >>= 1) s += __shfl_down(s, off);
        if (lane == 0) wf[outoff + c] = s + bs[c];
    } else if (bid == 384){
        wf[W3_OFF + tid] = ln3w[tid] * n3g[tid];
        for (int i = tid; i < 2560; i += 256) wf[P3_OFF + i] = p3w[i] * pn3g[i & 255];
    } else {
        const int g32 = tid >> 5, l32 = tid & 31;
        const int d = (bid - 385)*8 + g32;                   // 0..15, valid < 11
        if (d < 11){
            const float* w  = (d == 0) ? ln3w : (p3w + (d-1)*256);
            const float* nb = (d == 0) ? n3b  : pn3b;
            float s = 0.f;
            for (int k = l32; k < 256; k += 32) s += w[k] * nb[k];
            for (int off = 16; off; off >>= 1) s += __shfl_xor(s, off);
            if (l32 == 0){
                if (d == 0) wf[B3_OFF] = s + ln3b[0];
                else        wf[PB3_OFF + d - 1] = s + p3b[d - 1];
            }
        }
    }
}

// ---------------- main ------------------------------------------------------
// GEMM: sOut[32x256] = relu( sIn[32 x 32*FULLKC] @ W'^T + b' ).
// 4 waves x 64 cols; B frags double-buffered from global (L2-hot weights).
// INPLACE: barrier between K-loop reads and epilogue writes (sOut == sIn ok).
template<int FULLKC, bool INPLACE>
__device__ __forceinline__ void gemm32(
    const ushort_t* sIn, int astride, const ushort_t* __restrict__ Wg, int wstride,
    const float* __restrict__ biasf, ushort_t* sOut, int tid)
{
    const int lane = tid & 63, wave = tid >> 6;
    const int l15 = lane & 15, quad = lane >> 4;
    const int colbase = wave * 64;
    const ushort_t* ar0 = sIn + l15*astride + quad*8;
    const ushort_t* ar1 = ar0 + 16*astride;
    const ushort_t* wp[4];
#pragma unroll
    for (int nt = 0; nt < 4; ++nt)
        wp[nt] = Wg + (size_t)(colbase + nt*16 + l15) * wstride + quad*8;

    floatx4 acc[4][2];
#pragma unroll
    for (int nt = 0; nt < 4; ++nt){ acc[nt][0] = (floatx4){0,0,0,0}; acc[nt][1] = (floatx4){0,0,0,0}; }

    short8 bcur[4];
#pragma unroll
    for (int nt = 0; nt < 4; ++nt) bcur[nt] = *(const short8*)(wp[nt]);

#pragma unroll
    for (int kc = 0; kc < FULLKC; ++kc){
        const int kb = kc * 32;
        short8 bnxt[4];
        if (kc + 1 < FULLKC){
#pragma unroll
            for (int nt = 0; nt < 4; ++nt) bnxt[nt] = *(const short8*)(wp[nt] + kb + 32);
        }
        short8 a0 = *(const short8*)(ar0 + kb);
        short8 a1 = *(const short8*)(ar1 + kb);
#pragma unroll
        for (int nt = 0; nt < 4; ++nt){
            acc[nt][0] = __builtin_amdgcn_mfma_f32_16x16x32_bf16(a0, bcur[nt], acc[nt][0], 0, 0, 0);
            acc[nt][1] = __builtin_amdgcn_mfma_f32_16x16x32_bf16(a1, bcur[nt], acc[nt][1], 0, 0, 0);
        }
        if (kc + 1 < FULLKC){
#pragma unroll
            for (int nt = 0; nt < 4; ++nt) bcur[nt] = bnxt[nt];
        }
    }
    if (INPLACE) __syncthreads();   // all waves done reading sIn before writes
    // epilogue: C/D layout col=lane&15, row=quad*4+i
#pragma unroll
    for (int nt = 0; nt < 4; ++nt){
        const int col = colbase + nt*16 + l15;
        const float bia = biasf[col];
#pragma unroll
        for (int s2 = 0; s2 < 2; ++s2){
#pragma unroll
            for (int i = 0; i < 4; ++i){
                const int row = s2*16 + quad*4 + i;
                float v = acc[nt][s2][i] + bia;
                v = fmaxf(v, 0.f);
                sOut[row*SH + col] = f2b(v);
            }
        }
    }
}

// in-place plain LN over 32 rows x 256 cols of sB (gain/bias folded downstream)
__device__ __forceinline__ void ln256(
    ushort_t* sB, float* sRed, float* sM, float* sR, int tid)
{
    const int r = tid >> 3, p = tid & 7;
    const ushort_t* hp = sB + r*SH + p*32;
    float s = 0.f, sq = 0.f;
#pragma unroll
    for (int c = 0; c < 32; ++c){ float x = b2f(hp[c]); s += x; sq += x*x; }
    sRed[tid] = s; sRed[256 + tid] = sq;
    __syncthreads();
    if (tid < 32){
        float ss = 0.f, qq = 0.f;
#pragma unroll
        for (int j = 0; j < 8; ++j){ ss += sRed[tid*8 + j]; qq += sRed[256 + tid*8 + j]; }
        float m = ss * (1.f/256.f);
        float var = fmaxf(qq * (1.f/256.f) - m*m, 0.f);
        sM[tid] = m; sR[tid] = rsqrtf(var + 1e-5f);
    }
    __syncthreads();
#pragma unroll 4
    for (int r2 = 0; r2 < 32; ++r2)
        sB[r2*SH + tid] = f2b((b2f(sB[r2*SH + tid]) - sM[r2]) * sR[r2]);
    __syncthreads();
}

__global__ __launch_bounds__(256, 4) void bcq_main(
    const float* __restrict__ cum, const float* __restrict__ inp, const float* __restrict__ pos,
    const ushort_t* __restrict__ wbf, const float* __restrict__ wf, float* __restrict__ out)
{
    __shared__ __align__(16) char sMem[40192];     // 4 blocks/CU (160 KiB LDS)
    ushort_t* sX     = (ushort_t*)sMem;            // 20992 B: x-hat, both towers
    ushort_t* sHH    = (ushort_t*)(sMem + 20992);  // 16896 B: h (in-place per layer)
    float*    sRed   = (float*)(sMem + 37888);     // 2048 B (score buf aliases this)
    float*    sScore = sRed;                       // 1280 B, used only at the end
    float*    sM     = (float*)(sMem + 39936);     // 128 B
    float*    sR     = (float*)(sMem + 40064);     // 128 B

    const int tid = threadIdx.x;
    const int r8 = tid >> 3, p8 = tid & 7;
    const size_t rowg = (size_t)blockIdx.x * BM;

    // ---- phase 0: x in registers (8 thr/row), LN1 stats, build x-hat ----
    float v[37];
    {
        const float* cr = cum + (rowg + r8)*146;
        const float* ir = inp + (rowg + r8)*136;
        const float* pr = pos + (rowg + r8)*10;
        float s = 0.f, sq = 0.f;
#pragma unroll
        for (int i = 0; i < 37; ++i){
            const int c = p8 + (i << 3);
            float x = 0.f;
            if (c < 292){
                x = (c < 146) ? cr[c] : (c < 282) ? ir[c-146] : pr[c-282];
                s += x; sq += x*x;
            }
            v[i] = x;
        }
        sRed[tid] = s; sRed[256 + tid] = sq;
        // zero sX cols [292,324) (reads stop at 320; 320..323 harmless, in-stride)
#pragma unroll
        for (int j = 0; j < 4; ++j){
            const int c = 292 + p8 + (j << 3);
            if (c < SX) sX[r8*SX + c] = 0;
        }
    }
    __syncthreads();
    if (tid < 32){
        float ss = 0.f, qq = 0.f;
#pragma unroll
        for (int j = 0; j < 8; ++j){ ss += sRed[tid*8 + j]; qq += sRed[256 + tid*8 + j]; }
        float m = ss * (1.f/292.f);
        float var = fmaxf(qq * (1.f/292.f) - m*m, 0.f);
        sM[tid] = m; sR[tid] = rsqrtf(var + 1e-5f);
    }
    __syncthreads();
    {
        const float mr = sM[r8], rs = sR[r8];
#pragma unroll
        for (int i = 0; i < 37; ++i){
            const int c = p8 + (i << 3);
            if (c < 292) sX[r8*SX + c] = f2b((v[i] - mr) * rs);
        }
    }
    __syncthreads();

    // ================= value tower =================
    gemm32<10,false>(sX, SX, wbf + W1_OFF, KS1, wf + B1_OFF, sHH, tid);
    __syncthreads();
    ln256(sHH, sRed, sM, sR, tid);
    gemm32<8,true>(sHH, SH, wbf + W2_OFF, 256, wf + B2_OFF, sHH, tid);
    __syncthreads();
    ln256(sHH, sRed, sM, sR, tid);
    {   // value head
        const ushort_t* ap = sHH + r8*SH + p8*32;
        const float* w3 = wf + W3_OFF + p8*32;
        float s = 0.f;
#pragma unroll
        for (int c = 0; c < 32; ++c) s += b2f(ap[c]) * w3[c];
        sRed[tid] = s;
        __syncthreads();
        if (tid < 32){
            float vv = wf[B3_OFF];
#pragma unroll
            for (int j = 0; j < 8; ++j) vv += sRed[tid*8 + j];
            out[rowg + tid] = vv;
        }
        __syncthreads();
    }

    // ================= probability tower =================
    gemm32<10,false>(sX, SX, wbf + P1_OFF, KS1, wf + PB1_OFF, sHH, tid);
    __syncthreads();
    ln256(sHH, sRed, sM, sR, tid);
    gemm32<8,true>(sHH, SH, wbf + P2_OFF, 256, wf + PB2_OFF, sHH, tid);
    __syncthreads();
    ln256(sHH, sRed, sM, sR, tid);
    {   // score head (256->10) + log_softmax
        for (int s2 = tid; s2 < 320; s2 += 256){
            const int r = s2 / 10, j = s2 - r*10;
            const ushort_t* ap = sHH + r*SH;
            const float* pw = wf + P3_OFF + j*256;
            float acc = 0.f;
            for (int c = 0; c < 256; ++c) acc += b2f(ap[c]) * pw[c];
            sScore[s2] = acc + wf[PB3_OFF + j];
        }
        __syncthreads();
        if (tid < 32){
            float m = -1e30f;
#pragma unroll
            for (int j = 0; j < 10; ++j) m = fmaxf(m, sScore[tid*10 + j]);
            float l = 0.f;
#pragma unroll
            for (int j = 0; j < 10; ++j) l += expf(sScore[tid*10 + j] - m);
            l = logf(l);
            const size_t rg = rowg + tid;
#pragma unroll
            for (int j = 0; j < 10; ++j){
                const float sv = sScore[tid*10 + j];
                out[(size_t)NROWS    + rg*10 + j] = sv - m - l;
                out[(size_t)NROWS*11 + rg*10 + j] = sv;
            }
        }
    }
}

extern "C" void kernel_launch(void* const* d_in, const int* in_sizes, int n_in,
                              void* d_out, int out_size, void* d_ws, size_t ws_size,
                              hipStream_t stream) {
    (void)in_sizes; (void)n_in; (void)ws_size; (void)out_size;
    const float* cum  = (const float*)d_in[0];
    const float* inp  = (const float*)d_in[1];
    const float* pos  = (const float*)d_in[2];
    const float* ln1w = (const float*)d_in[3];
    const float* ln1b = (const float*)d_in[4];
    const float* ln2w = (const float*)d_in[5];
    const float* ln2b = (const float*)d_in[6];
    const float* ln3w = (const float*)d_in[7];
    const float* ln3b = (const float*)d_in[8];
    const float* n1g  = (const float*)d_in[9];
    const float* n1b  = (const float*)d_in[10];
    const float* n2g  = (const float*)d_in[11];
    const float* n2b  = (const float*)d_in[12];
    const float* n3g  = (const float*)d_in[13];
    const float* n3b  = (const float*)d_in[14];
    const float* p1w  = (const float*)d_in[15];
    const float* p1b  = (const float*)d_in[16];
    const float* p2w  = (const float*)d_in[17];
    const float* p2b  = (const float*)d_in[18];
    const float* p3w  = (const float*)d_in[19];
    const float* p3b  = (const float*)d_in[20];
    const float* pn1g = (const float*)d_in[21];
    const float* pn1b = (const float*)d_in[22];
    const float* pn2g = (const float*)d_in[23];
    const float* pn2b = (const float*)d_in[24];
    const float* pn3g = (const float*)d_in[25];
    const float* pn3b = (const float*)d_in[26];

    ushort_t* wbf = (ushort_t*)d_ws;
    float*    wf  = (float*)((char*)d_ws + BF16_BYTES);
    float*    out = (float*)d_out;

    hipLaunchKernelGGL(bcq_prep, dim3(387), dim3(256), 0, stream,
        ln1w, ln1b, ln2w, ln2b, ln3w, ln3b,
        n1g, n1b, n2g, n2b, n3g, n3b,
        p1w, p1b, p2w, p2b, p3w, p3b,
        pn1g, pn1b, pn2g, pn2b, pn3g, pn3b,
        wbf, wf);

    hipLaunchKernelGGL(bcq_main, dim3(NROWS/BM), dim3(256), 0, stream,
        cum, inp, pos, wbf, wf, out);
}

// Round 5
// 498.124 us; speedup vs baseline: 1.3331x; 1.2392x over previous
//
#include <hip/hip_runtime.h>

typedef unsigned short ushort_t;
typedef unsigned int   uint_t;
typedef __attribute__((ext_vector_type(8))) short  short8;
typedef __attribute__((ext_vector_type(4))) float  floatx4;

#define NROWS 131072
#define BM    32
#define SX    328     // x-hat bf16 LDS row stride (ushorts); cols >=292 zeroed to 320
#define SH    264     // h bf16 LDS row stride (ushorts)

// d_ws bf16 region (ushort element offsets) — chunk-major: [kc][col(256)][k(32)]
#define W1_OFF 0        // 10 chunks
#define P1_OFF 81920    // 10 chunks
#define W2_OFF 163840   // 8 chunks
#define P2_OFF 229376   // 8 chunks
#define BF16_BYTES 589824
// d_ws float region (float element offsets, base = ws + BF16_BYTES)
#define B1_OFF  0
#define PB1_OFF 256
#define B2_OFF  512
#define PB2_OFF 768
#define W3_OFF  1024
#define P3_OFF  1280
#define B3_OFF  3840
#define PB3_OFF 3841

__device__ __forceinline__ float b2f(ushort_t u){
    union { uint_t i; float f; } v; v.i = ((uint_t)u) << 16; return v.f;
}
__device__ __forceinline__ ushort_t f2b(float f){
    union { uint_t i; float f; } v; v.f = f;
    uint_t b = v.i;
    b += 0x7FFFu + ((b >> 16) & 1u);   // RNE
    return (ushort_t)(b >> 16);
}

// ---------------- prologue: fold LN gain/bias into linears, fp32 -> bf16 ----
// Weight layout out: chunk-major [kc][col][32] so a wave's B-frag load is 1KB
// contiguous (16 consecutive 64B lines).
__global__ __launch_bounds__(256) void bcq_prep(
    const float* __restrict__ ln1w, const float* __restrict__ ln1b,
    const float* __restrict__ ln2w, const float* __restrict__ ln2b,
    const float* __restrict__ ln3w, const float* __restrict__ ln3b,
    const float* __restrict__ n1g,  const float* __restrict__ n1b,
    const float* __restrict__ n2g,  const float* __restrict__ n2b,
    const float* __restrict__ n3g,  const float* __restrict__ n3b,
    const float* __restrict__ p1w,  const float* __restrict__ p1b,
    const float* __restrict__ p2w,  const float* __restrict__ p2b,
    const float* __restrict__ p3w,  const float* __restrict__ p3b,
    const float* __restrict__ pn1g, const float* __restrict__ pn1b,
    const float* __restrict__ pn2g, const float* __restrict__ pn2b,
    const float* __restrict__ pn3g, const float* __restrict__ pn3b,
    ushort_t* __restrict__ wbf, float* __restrict__ wf)
{
    const int bid = blockIdx.x, tid = threadIdx.x;
    if (bid < 128){
        // layer 1 (K=292 padded to 320): W1 then P1
        for (int i = bid*256 + tid; i < 163840; i += 128*256){
            const int which = i / 81920;            // 0=W1, 1=P1
            const int r  = i - which*81920;
            const int kc = r >> 13;                  // /8192
            const int t  = r & 8191;
            const int c  = t >> 5, kk = t & 31;
            const int k  = kc*32 + kk;
            const float* src = which ? p1w  : ln1w;
            const float* g   = which ? pn1g : n1g;
            ushort_t v = 0;
            if (k < 292) v = f2b(src[c*292 + k] * g[k]);
            wbf[i] = v;
        }
        // layer 2 (K=256): W2 then P2
        for (int i = bid*256 + tid; i < 131072; i += 128*256){
            const int which = i >> 16;
            const int r  = i & 65535;
            const int kc = r >> 13;
            const int t  = r & 8191;
            const int c  = t >> 5, kk = t & 31;
            const int k  = kc*32 + kk;
            const float* src = which ? p2w  : ln2w;
            const float* g   = which ? pn2g : n2g;
            wbf[W2_OFF + i] = f2b(src[c*256 + k] * g[k]);
        }
    } else if (bid < 384){
        const int d = (bid - 128)*4 + (tid >> 6);
        const int lane = tid & 63;
        const float *w, *nb, *bs; int K, outoff; const int c = d & 255;
        if (d < 256)      { w = ln1w; nb = n1b;  bs = ln1b; K = 292; outoff = B1_OFF; }
        else if (d < 512) { w = p1w;  nb = pn1b; bs = p1b;  K = 292; outoff = PB1_OFF; }
        else if (d < 768) { w = ln2w; nb = n2b;  bs = ln2b; K = 256; outoff = B2_OFF; }
        else              { w = p2w;  nb = pn2b; bs = p2b;  K = 256; outoff = PB2_OFF; }
        float s = 0.f;
        for (int k = lane; k < K; k += 64) s += w[c*K + k] * nb[k];
        for (int off = 32; off; off >>= 1) s += __shfl_down(s, off);
        if (lane == 0) wf[outoff + c] = s + bs[c];
    } else if (bid == 384){
        wf[W3_OFF + tid] = ln3w[tid] * n3g[tid];
        for (int i = tid; i < 2560; i += 256) wf[P3_OFF + i] = p3w[i] * pn3g[i & 255];
    } else {
        const int g32 = tid >> 5, l32 = tid & 31;
        const int d = (bid - 385)*8 + g32;                   // valid < 11
        if (d < 11){
            const float* w  = (d == 0) ? ln3w : (p3w + (d-1)*256);
            const float* nb = (d == 0) ? n3b  : pn3b;
            float s = 0.f;
            for (int k = l32; k < 256; k += 32) s += w[k] * nb[k];
            for (int off = 16; off; off >>= 1) s += __shfl_xor(s, off);
            if (l32 == 0){
                if (d == 0) wf[B3_OFF] = s + ln3b[0];
                else        wf[PB3_OFF + d - 1] = s + p3b[d - 1];
            }
        }
    }
}

// ---------------- main ------------------------------------------------------
// GEMM: sOut[32x256] = relu( sIn[32 x 32*FULLKC] @ W'^T + b' ).
// 4 waves x 64 cols; W chunk-major; depth-2 register prefetch of B frags.
template<int FULLKC, bool INPLACE>
__device__ __forceinline__ void gemm32(
    const ushort_t* sIn, int astride, const ushort_t* __restrict__ Wg,
    const float* __restrict__ biasf, ushort_t* sOut, int tid)
{
    const int lane = tid & 63, wave = tid >> 6;
    const int l15 = lane & 15, quad = lane >> 4;
    const int colbase = wave * 64;
    const ushort_t* ar0 = sIn + l15*astride + quad*8;
    const ushort_t* ar1 = ar0 + 16*astride;
    // chunk-major: frag addr = (colbase + nt*16 + l15)*32 + quad*8 + kc*8192
    const ushort_t* wl = Wg + (colbase + l15)*32 + quad*8;

    floatx4 acc[4][2];
#pragma unroll
    for (int nt = 0; nt < 4; ++nt){ acc[nt][0] = (floatx4){0,0,0,0}; acc[nt][1] = (floatx4){0,0,0,0}; }

    short8 bb0[4], bb1[4];
#pragma unroll
    for (int nt = 0; nt < 4; ++nt) bb0[nt] = *(const short8*)(wl + nt*512);
#pragma unroll
    for (int nt = 0; nt < 4; ++nt) bb1[nt] = *(const short8*)(wl + nt*512 + 8192);

#pragma unroll
    for (int kc = 0; kc < FULLKC; ++kc){
        short8 bnew[4];
        if (kc + 2 < FULLKC){
#pragma unroll
            for (int nt = 0; nt < 4; ++nt)
                bnew[nt] = *(const short8*)(wl + nt*512 + (kc + 2)*8192);
        }
        short8 a0 = *(const short8*)(ar0 + kc*32);
        short8 a1 = *(const short8*)(ar1 + kc*32);
#pragma unroll
        for (int nt = 0; nt < 4; ++nt){
            const short8 bc = (kc & 1) ? bb1[nt] : bb0[nt];
            acc[nt][0] = __builtin_amdgcn_mfma_f32_16x16x32_bf16(a0, bc, acc[nt][0], 0, 0, 0);
            acc[nt][1] = __builtin_amdgcn_mfma_f32_16x16x32_bf16(a1, bc, acc[nt][1], 0, 0, 0);
        }
        if (kc + 2 < FULLKC){
#pragma unroll
            for (int nt = 0; nt < 4; ++nt){
                if (kc & 1) bb1[nt] = bnew[nt]; else bb0[nt] = bnew[nt];
            }
        }
    }
    if (INPLACE) __syncthreads();   // all waves done reading sIn before writes
    // epilogue: C/D layout col=lane&15, row=quad*4+i
#pragma unroll
    for (int nt = 0; nt < 4; ++nt){
        const int col = colbase + nt*16 + l15;
        const float bia = biasf[col];
#pragma unroll
        for (int s2 = 0; s2 < 2; ++s2){
#pragma unroll
            for (int i = 0; i < 4; ++i){
                const int row = s2*16 + quad*4 + i;
                float v = acc[nt][s2][i] + bia;
                v = fmaxf(v, 0.f);
                sOut[row*SH + col] = f2b(v);
            }
        }
    }
}

// in-place plain LN over 32 rows x 256 cols of sB (gain/bias folded downstream)
__device__ __forceinline__ void ln256(
    ushort_t* sB, float* sRed, float* sM, float* sR, int tid)
{
    const int r = tid >> 3, p = tid & 7;
    const ushort_t* hp = sB + r*SH + p*32;
    float s = 0.f, sq = 0.f;
#pragma unroll
    for (int c = 0; c < 32; ++c){ float x = b2f(hp[c]); s += x; sq += x*x; }
    sRed[tid] = s; sRed[256 + tid] = sq;
    __syncthreads();
    if (tid < 32){
        float ss = 0.f, qq = 0.f;
#pragma unroll
        for (int j = 0; j < 8; ++j){ ss += sRed[tid*8 + j]; qq += sRed[256 + tid*8 + j]; }
        float m = ss * (1.f/256.f);
        float var = fmaxf(qq * (1.f/256.f) - m*m, 0.f);
        sM[tid] = m; sR[tid] = rsqrtf(var + 1e-5f);
    }
    __syncthreads();
#pragma unroll 4
    for (int r2 = 0; r2 < 32; ++r2)
        sB[r2*SH + tid] = f2b((b2f(sB[r2*SH + tid]) - sM[r2]) * sR[r2]);
    __syncthreads();
}

__global__ __launch_bounds__(256)
__attribute__((amdgpu_waves_per_eu(4, 4)))       // pin 4 waves/EU -> 128-VGPR budget
void bcq_main(
    const float* __restrict__ cum, const float* __restrict__ inp, const float* __restrict__ pos,
    const ushort_t* __restrict__ wbf, const float* __restrict__ wf, float* __restrict__ out)
{
    __shared__ __align__(16) char sMem[40192];     // 4 blocks/CU (160 KiB LDS)
    ushort_t* sX     = (ushort_t*)sMem;            // 20992 B: x-hat, both towers
    ushort_t* sHH    = (ushort_t*)(sMem + 20992);  // 16896 B: h (in-place per layer)
    float*    sRed   = (float*)(sMem + 37888);     // 2048 B (score buf aliases this)
    float*    sScore = sRed;                       // 1280 B, used only at the end
    float*    sM     = (float*)(sMem + 39936);     // 128 B
    float*    sR     = (float*)(sMem + 40064);     // 128 B

    const int tid = threadIdx.x;
    const int r8 = tid >> 3, p8 = tid & 7;
    const size_t rowg = (size_t)blockIdx.x * BM;

    // ---- phase 0: x in registers (8 thr/row), LN1 stats, build x-hat ----
    float v[37];
    {
        const float* cr = cum + (rowg + r8)*146;
        const float* ir = inp + (rowg + r8)*136;
        const float* pr = pos + (rowg + r8)*10;
        float s = 0.f, sq = 0.f;
#pragma unroll
        for (int i = 0; i < 37; ++i){
            const int c = p8 + (i << 3);
            float x = 0.f;
            if (c < 292){
                x = (c < 146) ? cr[c] : (c < 282) ? ir[c-146] : pr[c-282];
                s += x; sq += x*x;
            }
            v[i] = x;
        }
        sRed[tid] = s; sRed[256 + tid] = sq;
        // zero sX cols [292,324) (A reads stop at 320)
#pragma unroll
        for (int j = 0; j < 4; ++j){
            const int c = 292 + p8 + (j << 3);
            if (c < SX) sX[r8*SX + c] = 0;
        }
    }
    __syncthreads();
    if (tid < 32){
        float ss = 0.f, qq = 0.f;
#pragma unroll
        for (int j = 0; j < 8; ++j){ ss += sRed[tid*8 + j]; qq += sRed[256 + tid*8 + j]; }
        float m = ss * (1.f/292.f);
        float var = fmaxf(qq * (1.f/292.f) - m*m, 0.f);
        sM[tid] = m; sR[tid] = rsqrtf(var + 1e-5f);
    }
    __syncthreads();
    {
        const float mr = sM[r8], rs = sR[r8];
#pragma unroll
        for (int i = 0; i < 37; ++i){
            const int c = p8 + (i << 3);
            if (c < 292) sX[r8*SX + c] = f2b((v[i] - mr) * rs);
        }
    }
    __syncthreads();

    // ================= value tower =================
    gemm32<10,false>(sX, SX, wbf + W1_OFF, wf + B1_OFF, sHH, tid);
    __syncthreads();
    ln256(sHH, sRed, sM, sR, tid);
    gemm32<8,true>(sHH, SH, wbf + W2_OFF, wf + B2_OFF, sHH, tid);
    __syncthreads();
    ln256(sHH, sRed, sM, sR, tid);
    {   // value head
        const ushort_t* ap = sHH + r8*SH + p8*32;
        const float* w3 = wf + W3_OFF + p8*32;
        float s = 0.f;
#pragma unroll
        for (int c = 0; c < 32; ++c) s += b2f(ap[c]) * w3[c];
        sRed[tid] = s;
        __syncthreads();
        if (tid < 32){
            float vv = wf[B3_OFF];
#pragma unroll
            for (int j = 0; j < 8; ++j) vv += sRed[tid*8 + j];
            out[rowg + tid] = vv;
        }
        __syncthreads();
    }

    // ================= probability tower =================
    gemm32<10,false>(sX, SX, wbf + P1_OFF, wf + PB1_OFF, sHH, tid);
    __syncthreads();
    ln256(sHH, sRed, sM, sR, tid);
    gemm32<8,true>(sHH, SH, wbf + P2_OFF, wf + PB2_OFF, sHH, tid);
    __syncthreads();
    ln256(sHH, sRed, sM, sR, tid);
    {   // score head (256->10) + log_softmax
        for (int s2 = tid; s2 < 320; s2 += 256){
            const int r = s2 / 10, j = s2 - r*10;
            const ushort_t* ap = sHH + r*SH;
            const float* pw = wf + P3_OFF + j*256;
            float acc = 0.f;
            for (int c = 0; c < 256; ++c) acc += b2f(ap[c]) * pw[c];
            sScore[s2] = acc + wf[PB3_OFF + j];
        }
        __syncthreads();
        if (tid < 32){
            float m = -1e30f;
#pragma unroll
            for (int j = 0; j < 10; ++j) m = fmaxf(m, sScore[tid*10 + j]);
            float l = 0.f;
#pragma unroll
            for (int j = 0; j < 10; ++j) l += expf(sScore[tid*10 + j] - m);
            l = logf(l);
            const size_t rg = rowg + tid;
#pragma unroll
            for (int j = 0; j < 10; ++j){
                const float sv = sScore[tid*10 + j];
                out[(size_t)NROWS    + rg*10 + j] = sv - m - l;
                out[(size_t)NROWS*11 + rg*10 + j] = sv;
            }
        }
    }
}

extern "C" void kernel_launch(void* const* d_in, const int* in_sizes, int n_in,
                              void* d_out, int out_size, void* d_ws, size_t ws_size,
                              hipStream_t stream) {
    (void)in_sizes; (void)n_in; (void)ws_size; (void)out_size;
    const float* cum  = (const float*)d_in[0];
    const float* inp  = (const float*)d_in[1];
    const float* pos  = (const float*)d_in[2];
    const float* ln1w = (const float*)d_in[3];
    const float* ln1b = (const float*)d_in[4];
    const float* ln2w = (const float*)d_in[5];
    const float* ln2b = (const float*)d_in[6];
    const float* ln3w = (const float*)d_in[7];
    const float* ln3b = (const float*)d_in[8];
    const float* n1g  = (const float*)d_in[9];
    const float* n1b  = (const float*)d_in[10];
    const float* n2g  = (const float*)d_in[11];
    const float* n2b  = (const float*)d_in[12];
    const float* n3g  = (const float*)d_in[13];
    const float* n3b  = (const float*)d_in[14];
    const float* p1w  = (const float*)d_in[15];
    const float* p1b  = (const float*)d_in[16];
    const float* p2w  = (const float*)d_in[17];
    const float* p2b  = (const float*)d_in[18];
    const float* p3w  = (const float*)d_in[19];
    const float* p3b  = (const float*)d_in[20];
    const float* pn1g = (const float*)d_in[21];
    const float* pn1b = (const float*)d_in[22];
    const float* pn2g = (const float*)d_in[23];
    const float* pn2b = (const float*)d_in[24];
    const float* pn3g = (const float*)d_in[25];
    const float* pn3b = (const float*)d_in[26];

    ushort_t* wbf = (ushort_t*)d_ws;
    float*    wf  = (float*)((char*)d_ws + BF16_BYTES);
    float*    out = (float*)d_out;

    hipLaunchKernelGGL(bcq_prep, dim3(387), dim3(256), 0, stream,
        ln1w, ln1b, ln2w, ln2b, ln3w, ln3b,
        n1g, n1b, n2g, n2b, n3g, n3b,
        p1w, p1b, p2w, p2b, p3w, p3b,
        pn1g, pn1b, pn2g, pn2b, pn3g, pn3b,
        wbf, wf);

    hipLaunchKernelGGL(bcq_main, dim3(NROWS/BM), dim3(256), 0, stream,
        cum, inp, pos, wbf, wf, out);
}